// Round 8
// baseline (281.592 us; speedup 1.0000x reference)
//
#include <hip/hip_runtime.h>
#include <hip/hip_fp16.h>
#include <math.h>

#define NEG_SLOPE 0.2f
#define BN_EPS_F 1e-5f
#define NUM_G 500
#define NBUK_MAX 128
#define CHUNK 4096

typedef float v2f __attribute__((ext_vector_type(2)));

__device__ __forceinline__ float leaky(float x){ return x > 0.f ? x : NEG_SLOPE*x; }
__device__ __forceinline__ float bcast(float v, int k){
  return __int_as_float(__builtin_amdgcn_readlane(__float_as_int(v), k));
}

// ============ K1: fused bucket-hist + batch-hist + lin1 (role split by blockIdx) ============
#define HB 256
#define BB 64
#define L1B 512
__global__ __launch_bounds__(256) void fused_hist_lin1_kernel(
    const int* __restrict__ edst, int E, int* __restrict__ bukcnt,
    int bshift, int nbuk,
    const int* __restrict__ batch, int* __restrict__ gcnt,
    const float* __restrict__ x, const float* __restrict__ W,
    const float* __restrict__ att_s, const float* __restrict__ att_d,
    unsigned char* __restrict__ xh, float* __restrict__ a_src, float* __restrict__ a_dst, int N)
{
  __shared__ int lhist[NUM_G];
  int t = threadIdx.x;
  int bid = blockIdx.x;
  if (bid < HB) {
    if (t < NBUK_MAX) lhist[t] = 0;
    __syncthreads();
    int i = bid*256 + t, stride = HB*256;
    for (; i < E; i += stride) atomicAdd(&lhist[edst[i] >> bshift], 1);
    __syncthreads();
    if (t < nbuk && lhist[t]) atomicAdd(&bukcnt[t], lhist[t]);
  } else if (bid < HB + BB) {
    for (int i = t; i < NUM_G; i += 256) lhist[i] = 0;
    __syncthreads();
    int i = (bid-HB)*256 + t, stride = BB*256;
    for (; i < N; i += stride) atomicAdd(&lhist[batch[i]], 1);
    __syncthreads();
    for (int i = t; i < NUM_G; i += 256) if (lhist[i]) atomicAdd(&gcnt[i], lhist[i]);
  } else {
    int lane = t & 63;
    int wid  = ((bid - HB - BB)*256 + t) >> 6;
    int nw   = (L1B*256) >> 6;
    float w[32];
    #pragma unroll
    for (int k = 0; k < 32; ++k) w[k] = W[k*64 + lane];
    float asv = att_s[lane], adv = att_d[lane];
    for (int n = wid; n < N; n += nw) {
      float xv = (lane < 32) ? x[(size_t)n*32 + lane] : 0.f;
      float acc = 0.f;
      #pragma unroll
      for (int k = 0; k < 32; ++k) acc = fmaf(bcast(xv, k), w[k], acc);
      float sv = acc*asv, dv = acc*adv;
      #pragma unroll
      for (int m = 1; m < 16; m <<= 1) { sv += __shfl_xor(sv, m); dv += __shfl_xor(dv, m); }
      // fp8 e4m3 pack: even lane stores (own, partner) as 2 bytes
      float accp = __shfl_xor(acc, 1);
      if ((lane & 1) == 0) {
        int p = __builtin_amdgcn_cvt_pk_fp8_f32(acc, accp, 0, false);
        *(unsigned short*)(xh + (size_t)n*64 + lane) = (unsigned short)(p & 0xffff);
      }
      if ((lane & 15) == 0) { a_src[n*4 + (lane>>4)] = sv; a_dst[n*4 + (lane>>4)] = dv; }
    }
  }
}

// ============ K2: two exclusive scans in one launch ============
__global__ __launch_bounds__(1024) void exscan2_kernel(
    const int* __restrict__ in0, int* __restrict__ out0, int n0,
    const int* __restrict__ in1, int* __restrict__ out1, int n1)
{
  const int* in  = blockIdx.x ? in1  : in0;
  int*       out = blockIdx.x ? out1 : out0;
  int        n   = blockIdx.x ? n1   : n0;
  __shared__ int part[1024];
  int t = threadIdx.x;
  int per = (n + 1023) >> 10;
  int lo = t*per, hi = lo + per; if (lo > n) lo = n; if (hi > n) hi = n;
  int s = 0;
  for (int i = lo; i < hi; ++i) s += in[i];
  part[t] = s;
  __syncthreads();
  for (int ofs = 1; ofs < 1024; ofs <<= 1) {
    int v = (t >= ofs) ? part[t-ofs] : 0;
    __syncthreads();
    part[t] += v;
    __syncthreads();
  }
  int base = part[t] - s;
  for (int i = lo; i < hi; ++i) { out[i] = base; base += in[i]; }
  if (t == 1023) out[n] = part[1023];
}

// ============ K3: binned scatter ============
__global__ __launch_bounds__(256) void binscat_kernel(
    const int* __restrict__ esrc, const int* __restrict__ edst, int E,
    const int* __restrict__ bukoff, int* __restrict__ bukcur,
    int2* __restrict__ pairs, int bshift, int nbuk)
{
  __shared__ int hist[NBUK_MAX];
  __shared__ int loffs[NBUK_MAX];
  __shared__ int gbase[NBUK_MAX];
  __shared__ int2 stage[CHUNK];
  int t = threadIdx.x;
  for (int c0 = blockIdx.x*CHUNK; c0 < E; c0 += gridDim.x*CHUNK) {
    int cnt = E - c0; if (cnt > CHUNK) cnt = CHUNK;
    if (t < NBUK_MAX) hist[t] = 0;
    __syncthreads();
    for (int i = t; i < cnt; i += 256)
      atomicAdd(&hist[edst[c0+i] >> bshift], 1);
    __syncthreads();
    int cb = (t < nbuk) ? hist[t] : 0;
    for (int ofs = 1; ofs < nbuk; ofs <<= 1) {
      int v = (t < nbuk && t >= ofs) ? hist[t-ofs] : 0;
      __syncthreads();
      if (t < nbuk) hist[t] += v;
      __syncthreads();
    }
    if (t < nbuk) {
      int lo = hist[t] - cb;
      loffs[t] = lo;
      int base = atomicAdd(&bukcur[t], cb);
      gbase[t] = bukoff[t] + base - lo;
    }
    __syncthreads();
    if (t < nbuk) hist[t] = 0;
    __syncthreads();
    for (int i = t; i < cnt; i += 256) {
      int s = esrc[c0+i], d = edst[c0+i];
      int b = d >> bshift;
      int r = atomicAdd(&hist[b], 1);
      stage[loffs[b] + r] = make_int2(s, d);
    }
    __syncthreads();
    for (int j = t; j < cnt; j += 256) {
      int2 p = stage[j];
      pairs[gbase[p.y >> bshift] + j] = p;
    }
    __syncthreads();
  }
}

// ============ K4: per-bucket CSR build ============
__global__ __launch_bounds__(512) void bucket_csr_kernel(
    const int2* __restrict__ pairs, const int* __restrict__ bukoff,
    int* __restrict__ off, int* __restrict__ csr, int N, int E, int bshift)
{
  __shared__ int cnt[1024];
  __shared__ int cur[1024];
  __shared__ int part[512];
  int b = blockIdx.x, t = threadIdx.x;
  int base = b << bshift;
  int bnodes = 1 << bshift;
  int nlocal = N - base; if (nlocal > bnodes) nlocal = bnodes;
  int lo = bukoff[b], hi = bukoff[b+1];
  int gb = lo;
  for (int i = t; i < bnodes; i += 512) cnt[i] = 0;
  __syncthreads();
  for (int i = lo + t; i < hi; i += 512) atomicAdd(&cnt[pairs[i].y - base], 1);
  __syncthreads();
  int Wc = bnodes >> 9;
  int mys = 0;
  for (int j = 0; j < Wc; ++j) mys += cnt[t*Wc + j];
  part[t] = mys;
  __syncthreads();
  for (int ofs = 1; ofs < 512; ofs <<= 1) {
    int v = (t >= ofs) ? part[t-ofs] : 0;
    __syncthreads();
    part[t] += v;
    __syncthreads();
  }
  int ex = part[t] - mys;
  for (int j = 0; j < Wc; ++j) { int c = cnt[t*Wc + j]; cnt[t*Wc + j] = ex; ex += c; }
  __syncthreads();
  for (int i = t; i < nlocal; i += 512) off[base + i] = gb + cnt[i];
  if (b == 0 && t == 0) off[N] = E;
  for (int i = t; i < bnodes; i += 512) cur[i] = 0;
  __syncthreads();
  for (int i = lo + t; i < hi; i += 512) {
    int2 p = pairs[i];
    int l = p.y - base;
    int pos = gb + cnt[l] + atomicAdd(&cur[l], 1);
    csr[pos] = p.x;
  }
}

// ============ GAT agg layer 1 (F=64 fp8): 4 edges/iter, 16 lanes/edge, 4ch/lane ============
__global__ __launch_bounds__(256) void gat_agg1_kernel(
    const unsigned char* __restrict__ xh, const float* __restrict__ a_src, const float* __restrict__ a_dst,
    const int* __restrict__ off, const int* __restrict__ csr,
    const float* __restrict__ bias, const float* __restrict__ bng, const float* __restrict__ bnb,
    const float* __restrict__ bnrm, const float* __restrict__ bnrv,
    float* __restrict__ hout, int N)
{
  int lane = threadIdx.x & 63;
  int wid  = (blockIdx.x * blockDim.x + threadIdx.x) >> 6;
  int nw   = (gridDim.x * blockDim.x) >> 6;
  int g  = lane >> 4;        // edge slot 0..3
  int li = lane & 15;        // 16 lanes per edge
  int c0 = li * 4;           // channels c0..c0+3
  int h  = li >> 2;
  float sc[4], of[4];
  #pragma unroll
  for (int j = 0; j < 4; ++j) {
    sc[j] = rsqrtf(bnrv[c0+j]+BN_EPS_F) * bng[c0+j];
    of[j] = bias[c0+j]*sc[j] + bnb[c0+j] - bnrm[c0+j]*sc[j];
  }
  for (int n = wid; n < N; n += nw) {
    int lo = off[n], hi = off[n+1];
    float adh = a_dst[n*4+h];
    float es  = __expf(leaky(a_src[n*4+h] + adh));
    float acc0=0.f, acc1=0.f, acc2=0.f, acc3=0.f, ssum=0.f;
    for (int e = lo; e < hi; e += 4) {
      int ee = e + g; bool ok = ee < hi;
      int s = __builtin_nontemporal_load(csr + (ok ? ee : lo));
      float a = a_src[s*4+h];
      unsigned int rw = *(const unsigned int*)(xh + (size_t)s*64 + c0);
      float w = ok ? __expf(leaky(a+adh)) : 0.f;
      ssum += w;
      v2f flo = __builtin_amdgcn_cvt_pk_f32_fp8(rw, false);
      v2f fhi = __builtin_amdgcn_cvt_pk_f32_fp8(rw, true);
      acc0 = fmaf(w, flo.x, acc0); acc1 = fmaf(w, flo.y, acc1);
      acc2 = fmaf(w, fhi.x, acc2); acc3 = fmaf(w, fhi.y, acc3);
    }
    #pragma unroll
    for (int m = 16; m < 64; m <<= 1) {
      acc0 += __shfl_xor(acc0, m); acc1 += __shfl_xor(acc1, m);
      acc2 += __shfl_xor(acc2, m); acc3 += __shfl_xor(acc3, m);
      ssum += __shfl_xor(ssum, m);
    }
    // self loop
    unsigned int rw = *(const unsigned int*)(xh + (size_t)n*64 + c0);
    v2f flo = __builtin_amdgcn_cvt_pk_f32_fp8(rw, false);
    v2f fhi = __builtin_amdgcn_cvt_pk_f32_fp8(rw, true);
    acc0 = fmaf(es, flo.x, acc0); acc1 = fmaf(es, flo.y, acc1);
    acc2 = fmaf(es, fhi.x, acc2); acc3 = fmaf(es, fhi.y, acc3);
    ssum += es;
    float inv = 1.f / (ssum + 1e-16f);
    if (g == 0) {
      float4 r;
      r.x = fmaxf(fmaf(acc0*inv, sc[0], of[0]), 0.f);
      r.y = fmaxf(fmaf(acc1*inv, sc[1], of[1]), 0.f);
      r.z = fmaxf(fmaf(acc2*inv, sc[2], of[2]), 0.f);
      r.w = fmaxf(fmaf(acc3*inv, sc[3], of[3]), 0.f);
      *(float4*)(hout + (size_t)n*64 + c0) = r;
    }
  }
}

// ============ linear 2 (fp8 out) ============
__global__ __launch_bounds__(256) void lin2_kernel(
    const float* __restrict__ hin, const float* __restrict__ W,
    const float* __restrict__ att_s, const float* __restrict__ att_d,
    unsigned char* __restrict__ xh, float* __restrict__ a_src, float* __restrict__ a_dst, int N)
{
  int lane = threadIdx.x & 63;
  int wid  = (blockIdx.x * blockDim.x + threadIdx.x) >> 6;
  int nw   = (gridDim.x * blockDim.x) >> 6;
  float wa[64], wb[64];
  #pragma unroll
  for (int k = 0; k < 64; ++k) { wa[k] = W[k*128 + lane]; wb[k] = W[k*128 + 64 + lane]; }
  float asa = att_s[lane], ada = att_d[lane];
  float asb = att_s[64+lane], adb = att_d[64+lane];
  for (int n = wid; n < N; n += nw) {
    float hv = hin[(size_t)n*64 + lane];
    float a0 = 0.f, a1 = 0.f;
    #pragma unroll
    for (int k = 0; k < 64; ++k) {
      float h = bcast(hv, k);
      a0 = fmaf(h, wa[k], a0); a1 = fmaf(h, wb[k], a1);
    }
    float sva = a0*asa, dva = a0*ada, svb = a1*asb, dvb = a1*adb;
    #pragma unroll
    for (int m = 1; m < 32; m <<= 1) {
      sva += __shfl_xor(sva, m); dva += __shfl_xor(dva, m);
      svb += __shfl_xor(svb, m); dvb += __shfl_xor(dvb, m);
    }
    // fp8 pack: even lane stores (own, partner) pairs for both halves
    float b0 = __shfl_xor(a0, 1);
    float b1 = __shfl_xor(a1, 1);
    if ((lane & 1) == 0) {
      int p0 = __builtin_amdgcn_cvt_pk_fp8_f32(a0, b0, 0, false);
      int p1 = __builtin_amdgcn_cvt_pk_fp8_f32(a1, b1, 0, false);
      *(unsigned short*)(xh + (size_t)n*128 + lane)      = (unsigned short)(p0 & 0xffff);
      *(unsigned short*)(xh + (size_t)n*128 + 64 + lane) = (unsigned short)(p1 & 0xffff);
    }
    if ((lane & 31) == 0) {
      int hh = lane >> 5;
      a_src[n*4 + hh] = sva;     a_dst[n*4 + hh] = dva;
      a_src[n*4 + 2 + hh] = svb; a_dst[n*4 + 2 + hh] = dvb;
    }
  }
}

// ============ GAT agg layer 2 (F=128 fp8): 4 edges/iter, 16 lanes/edge, 8ch/lane ============
__global__ __launch_bounds__(256) void gat_agg2_kernel(
    const unsigned char* __restrict__ xh, const float* __restrict__ a_src, const float* __restrict__ a_dst,
    const int* __restrict__ off, const int* __restrict__ csr,
    const float* __restrict__ bias, const float* __restrict__ bng, const float* __restrict__ bnb,
    const float* __restrict__ bnrm, const float* __restrict__ bnrv,
    const float* __restrict__ gateW, const float* __restrict__ gateB,
    float* __restrict__ hout, float* __restrict__ gate, int N)
{
  int lane = threadIdx.x & 63;
  int wid  = (blockIdx.x * blockDim.x + threadIdx.x) >> 6;
  int nw   = (gridDim.x * blockDim.x) >> 6;
  int g  = lane >> 4;        // edge slot 0..3
  int li = lane & 15;        // 16 lanes per edge
  int c0 = li * 8;           // channels c0..c0+7
  int h  = li >> 2;
  float sc[8], of[8], gw[8];
  #pragma unroll
  for (int j = 0; j < 8; ++j) {
    sc[j] = rsqrtf(bnrv[c0+j]+BN_EPS_F) * bng[c0+j];
    of[j] = bias[c0+j]*sc[j] + bnb[c0+j] - bnrm[c0+j]*sc[j];
    gw[j] = gateW[c0+j];
  }
  float gb = gateB[0];
  for (int n = wid; n < N; n += nw) {
    int lo = off[n], hi = off[n+1];
    float adh = a_dst[n*4+h];
    float es  = __expf(leaky(a_src[n*4+h] + adh));
    float acc0=0.f, acc1=0.f, acc2=0.f, acc3=0.f;
    float acc4=0.f, acc5=0.f, acc6=0.f, acc7=0.f, ssum=0.f;
    for (int e = lo; e < hi; e += 4) {
      int ee = e + g; bool ok = ee < hi;
      int s = __builtin_nontemporal_load(csr + (ok ? ee : lo));
      float a = a_src[s*4+h];
      int2 rv = *(const int2*)(xh + (size_t)s*128 + c0);
      float w = ok ? __expf(leaky(a+adh)) : 0.f;
      ssum += w;
      v2f f0 = __builtin_amdgcn_cvt_pk_f32_fp8((unsigned)rv.x, false);
      v2f f1 = __builtin_amdgcn_cvt_pk_f32_fp8((unsigned)rv.x, true);
      v2f f2 = __builtin_amdgcn_cvt_pk_f32_fp8((unsigned)rv.y, false);
      v2f f3 = __builtin_amdgcn_cvt_pk_f32_fp8((unsigned)rv.y, true);
      acc0 = fmaf(w, f0.x, acc0); acc1 = fmaf(w, f0.y, acc1);
      acc2 = fmaf(w, f1.x, acc2); acc3 = fmaf(w, f1.y, acc3);
      acc4 = fmaf(w, f2.x, acc4); acc5 = fmaf(w, f2.y, acc5);
      acc6 = fmaf(w, f3.x, acc6); acc7 = fmaf(w, f3.y, acc7);
    }
    #pragma unroll
    for (int m = 16; m < 64; m <<= 1) {
      acc0 += __shfl_xor(acc0, m); acc1 += __shfl_xor(acc1, m);
      acc2 += __shfl_xor(acc2, m); acc3 += __shfl_xor(acc3, m);
      acc4 += __shfl_xor(acc4, m); acc5 += __shfl_xor(acc5, m);
      acc6 += __shfl_xor(acc6, m); acc7 += __shfl_xor(acc7, m);
      ssum += __shfl_xor(ssum, m);
    }
    // self loop
    int2 rv = *(const int2*)(xh + (size_t)n*128 + c0);
    v2f f0 = __builtin_amdgcn_cvt_pk_f32_fp8((unsigned)rv.x, false);
    v2f f1 = __builtin_amdgcn_cvt_pk_f32_fp8((unsigned)rv.x, true);
    v2f f2 = __builtin_amdgcn_cvt_pk_f32_fp8((unsigned)rv.y, false);
    v2f f3 = __builtin_amdgcn_cvt_pk_f32_fp8((unsigned)rv.y, true);
    acc0 = fmaf(es, f0.x, acc0); acc1 = fmaf(es, f0.y, acc1);
    acc2 = fmaf(es, f1.x, acc2); acc3 = fmaf(es, f1.y, acc3);
    acc4 = fmaf(es, f2.x, acc4); acc5 = fmaf(es, f2.y, acc5);
    acc6 = fmaf(es, f3.x, acc6); acc7 = fmaf(es, f3.y, acc7);
    ssum += es;
    float inv = 1.f / (ssum + 1e-16f);
    float r0 = fmaxf(fmaf(acc0*inv, sc[0], of[0]), 0.f);
    float r1 = fmaxf(fmaf(acc1*inv, sc[1], of[1]), 0.f);
    float r2 = fmaxf(fmaf(acc2*inv, sc[2], of[2]), 0.f);
    float r3 = fmaxf(fmaf(acc3*inv, sc[3], of[3]), 0.f);
    float r4 = fmaxf(fmaf(acc4*inv, sc[4], of[4]), 0.f);
    float r5 = fmaxf(fmaf(acc5*inv, sc[5], of[5]), 0.f);
    float r6 = fmaxf(fmaf(acc6*inv, sc[6], of[6]), 0.f);
    float r7 = fmaxf(fmaf(acc7*inv, sc[7], of[7]), 0.f);
    if (g == 0) {
      float4 w0 = make_float4(r0, r1, r2, r3);
      float4 w1 = make_float4(r4, r5, r6, r7);
      *(float4*)(hout + (size_t)n*128 + c0)     = w0;
      *(float4*)(hout + (size_t)n*128 + c0 + 4) = w1;
    }
    float gl = r0*gw[0] + r1*gw[1] + r2*gw[2] + r3*gw[3]
             + r4*gw[4] + r5*gw[5] + r6*gw[6] + r7*gw[7];
    #pragma unroll
    for (int m = 1; m < 16; m <<= 1) gl += __shfl_xor(gl, m);
    if (lane == 0) gate[n] = gl + gb;
  }
}

// ============ per-graph attention pooling + MLP heads ============
__global__ __launch_bounds__(128) void pool_kernel(
    const float* __restrict__ h2, const float* __restrict__ gate, const int* __restrict__ goff,
    const float* __restrict__ fc1W, const float* __restrict__ fc1b,
    const float* __restrict__ valW, const float* __restrict__ valb,
    const float* __restrict__ advW, const float* __restrict__ advb,
    float* __restrict__ out)
{
  int g = blockIdx.x, t = threadIdx.x;
  int lo = goff[g], hi = goff[g+1];
  __shared__ float red[2];
  __shared__ float pld[128];
  __shared__ float zs[32];
  __shared__ float sval;
  __shared__ float adv_s[16];

  float m = -3.4e38f;
  for (int n = lo+t; n < hi; n += 128) m = fmaxf(m, gate[n]);
  #pragma unroll
  for (int msk = 1; msk < 64; msk <<= 1) m = fmaxf(m, __shfl_xor(m, msk));
  if ((t & 63) == 0) red[t >> 6] = m;
  __syncthreads();
  m = fmaxf(red[0], red[1]);
  __syncthreads();
  float sl = 0.f;
  for (int n = lo+t; n < hi; n += 128) sl += __expf(gate[n]-m);
  #pragma unroll
  for (int msk = 1; msk < 64; msk <<= 1) sl += __shfl_xor(sl, msk);
  if ((t & 63) == 0) red[t >> 6] = sl;
  __syncthreads();
  float s = red[0] + red[1];
  float acc = 0.f;
  for (int n = lo; n < hi; ++n) {
    float w = __expf(gate[n]-m);
    acc += w * h2[(size_t)n*128 + t];
  }
  pld[t] = acc / (s + 1e-16f);
  __syncthreads();
  if (t < 32) {
    float z = fc1b[t];
    #pragma unroll 4
    for (int k = 0; k < 128; ++k) z += pld[k]*fc1W[k*32 + t];
    zs[t] = fmaxf(z, 0.f);
  }
  __syncthreads();
  if (t < 32) {
    float pv = zs[t]*valW[t];
    #pragma unroll
    for (int msk = 1; msk < 32; msk <<= 1) pv += __shfl_xor(pv, msk);
    if (t == 0) sval = pv + valb[0];
  }
  if (t < 16) {
    float a = advb[t];
    #pragma unroll
    for (int k = 0; k < 32; ++k) a += zs[k]*advW[k*16 + t];
    adv_s[t] = a;
  }
  __syncthreads();
  if (t < 16) {
    float amean = adv_s[t];
    #pragma unroll
    for (int msk = 1; msk < 16; msk <<= 1) amean += __shfl_xor(amean, msk);
    amean *= (1.f/16.f);
    out[g*16 + t] = sval + adv_s[t] - amean;
  }
}

extern "C" void kernel_launch(void* const* d_in, const int* in_sizes, int n_in,
                              void* d_out, int out_size, void* d_ws, size_t ws_size,
                              hipStream_t stream)
{
  const float* x     = (const float*)d_in[0];
  const int*   eidx  = (const int*)  d_in[1];
  const int*   batch = (const int*)  d_in[2];
  const float* W1    = (const float*)d_in[3];
  const float* as1w  = (const float*)d_in[4];
  const float* ad1w  = (const float*)d_in[5];
  const float* b1    = (const float*)d_in[6];
  const float* bn1g  = (const float*)d_in[7];
  const float* bn1b  = (const float*)d_in[8];
  const float* bn1rm = (const float*)d_in[9];
  const float* bn1rv = (const float*)d_in[10];
  const float* W2    = (const float*)d_in[11];
  const float* as2w  = (const float*)d_in[12];
  const float* ad2w  = (const float*)d_in[13];
  const float* b2    = (const float*)d_in[14];
  const float* bn2g  = (const float*)d_in[15];
  const float* bn2b  = (const float*)d_in[16];
  const float* bn2rm = (const float*)d_in[17];
  const float* bn2rv = (const float*)d_in[18];
  const float* gateW = (const float*)d_in[19];
  const float* gateB = (const float*)d_in[20];
  const float* fc1W  = (const float*)d_in[21];
  const float* fc1b  = (const float*)d_in[22];
  const float* valW  = (const float*)d_in[23];
  const float* valb  = (const float*)d_in[24];
  const float* advW  = (const float*)d_in[25];
  const float* advb  = (const float*)d_in[26];

  int N = in_sizes[0] / 32;
  int E = in_sizes[1] / 2;
  const int* esrc = eidx;
  const int* edst = eidx + E;

  int bshift = 9;
  while ((((N - 1) >> bshift) + 1) > NBUK_MAX) ++bshift;
  int nbuk = ((N - 1) >> bshift) + 1;

  float* ws = (float*)d_ws;
  size_t o = 0;
  unsigned char* xh1q = (unsigned char*)(ws + o); o += (size_t)N*16;   // N*64 fp8 bytes
  unsigned char* xh2q = (unsigned char*)(ws + o); o += (size_t)N*32;   // N*128 fp8 bytes
  float* as1 = ws + o; o += (size_t)N*4;
  float* ad1 = ws + o; o += (size_t)N*4;
  float* as2 = ws + o; o += (size_t)N*4;
  float* ad2 = ws + o; o += (size_t)N*4;
  float* h1  = ws + o; o += (size_t)N*64;
  float* h2  = ws + o; o += (size_t)N*128;
  float* gate = ws + o; o += (size_t)N;
  if (o & 1) ++o;
  int2* pairs = (int2*)(ws + o); o += (size_t)E*2;
  int* ib     = (int*)(ws + o);
  int* gcnt   = ib;
  int* bukcnt = ib + 512;
  int* bukcur = ib + 640;
  size_t zcnt = 768;
  int* off    = ib + zcnt;                 // N+1
  int* goff   = off + (N+1);               // NUM_G+1
  int* bukoff = goff + (NUM_G+1);          // nbuk+1
  int* csr    = bukoff + (NBUK_MAX+1);     // E

  hipMemsetAsync(gcnt, 0, zcnt*sizeof(int), stream);

  fused_hist_lin1_kernel<<<HB+BB+L1B, 256, 0, stream>>>(
      edst, E, bukcnt, bshift, nbuk, batch, gcnt,
      x, W1, as1w, ad1w, xh1q, as1, ad1, N);
  exscan2_kernel<<<2, 1024, 0, stream>>>(bukcnt, bukoff, nbuk, gcnt, goff, NUM_G);
  int nchunk = (E + CHUNK - 1) / CHUNK;
  binscat_kernel<<<nchunk, 256, 0, stream>>>(esrc, edst, E, bukoff, bukcur, pairs, bshift, nbuk);
  bucket_csr_kernel<<<nbuk, 512, 0, stream>>>(pairs, bukoff, off, csr, N, E, bshift);
  gat_agg1_kernel<<<2048, 256, 0, stream>>>(xh1q, as1, ad1, off, csr,
      b1, bn1g, bn1b, bn1rm, bn1rv, h1, N);
  lin2_kernel<<<1024, 256, 0, stream>>>(h1, W2, as2w, ad2w, xh2q, as2, ad2, N);
  gat_agg2_kernel<<<2048, 256, 0, stream>>>(xh2q, as2, ad2, off, csr,
      b2, bn2g, bn2b, bn2rm, bn2rv, gateW, gateB, h2, gate, N);
  pool_kernel<<<NUM_G, 128, 0, stream>>>(h2, gate, goff, fc1W, fc1b, valW, valb, advW, advb,
      (float*)d_out);
}